// Round 2
// baseline (315.965 us; speedup 1.0000x reference)
//
#include <hip/hip_runtime.h>
#include <hip/hip_bf16.h>

#define BATCH 4
#define NPTS  8192
#define SPTS  2048
#define C1    128
#define C2    256
#define CIN   384   // C1+C2
#define H0    256
#define H1    128

typedef __attribute__((ext_vector_type(8))) short bf16x8;
typedef __attribute__((ext_vector_type(4))) float f32x4;

__device__ __forceinline__ unsigned short f2bf(float x) {
  union { float f; unsigned u; } v; v.f = x;
  unsigned r = v.u + 0x7fff + ((v.u >> 16) & 1);   // RNE
  return (unsigned short)(r >> 16);
}
__device__ __forceinline__ float bf2f(unsigned short u) {
  union { unsigned u; float f; } v; v.u = ((unsigned)u) << 16; return v.f;
}

// ---------------- fused prep: all input-only packing in one launch ----------------
// seg A [0,512):    transpose points2 (B,C2,S) fp32 -> p2tb (B,S,C2) bf16
// seg B [512,1024): pack points1 (B,C1,N) fp32 -> Xp[b][n][0..127] bf16
// seg C [1024,1056): prepack xyz2 (B,3,S) -> float4 (x,y,z,|c|^2)
// seg D [1056,1184): weights fp32 -> bf16 (Wp0 256x384, then Wp1 128x256)
// seg E [1184]:      zero BN stat accumulators (sum0,sq0,sum1,sq1)
__global__ __launch_bounds__(256) void prep_kernel(
    const float* __restrict__ p2, unsigned short* __restrict__ p2tb,
    const float* __restrict__ xyz2, float4* __restrict__ xp,
    const float* __restrict__ w0, const float* __restrict__ w1,
    unsigned short* __restrict__ Wp,
    const float* __restrict__ p1, unsigned short* __restrict__ Xp,
    float* __restrict__ stats) {
  __shared__ unsigned short shmem[64 * 136];
  int bid = blockIdx.x;
  int t = threadIdx.x;

  if (bid < 512) {  // ---- transpose p2 -> bf16 ----
    int b = bid >> 7, rem = bid & 127;
    int s0 = (rem >> 2) * 64, c0 = (rem & 3) * 64;
    const float* src = p2 + (size_t)b * C2 * SPTS;
    int ss = t & 63, cseg = t >> 6;
#pragma unroll
    for (int i = 0; i < 16; i++) {
      int cc = cseg + i * 4;
      shmem[ss * 72 + cc] = f2bf(src[(size_t)(c0 + cc) * SPTS + s0 + ss]);
    }
    __syncthreads();
    int s = t >> 2, chunk = t & 3;
    uint4 v0 = *(const uint4*)&shmem[s * 72 + chunk * 16];
    uint4 v1 = *(const uint4*)&shmem[s * 72 + chunk * 16 + 8];
    unsigned short* dst = p2tb + (size_t)b * SPTS * C2 + (size_t)(s0 + s) * C2 + c0 + chunk * 16;
    *(uint4*)dst = v0;
    *(uint4*)(dst + 8) = v1;
  } else if (bid < 1024) {  // ---- pack p1 ----
    int b2 = bid - 512;
    int b = b2 >> 7, n0 = (b2 & 127) * 64;
    int nn = t & 63, c4 = t >> 6;
#pragma unroll
    for (int i = 0; i < 32; i++) {
      int c = i * 4 + c4;
      shmem[nn * 136 + c] = f2bf(p1[((size_t)b * C1 + c) * NPTS + n0 + nn]);
    }
    __syncthreads();
    int n = t >> 2;
#pragma unroll
    for (int j = 0; j < 4; j++) {
      int ch = (t & 3) + j * 4;
      uint4 v = *(const uint4*)&shmem[n * 136 + ch * 8];
      *(uint4*)&Xp[((size_t)b * NPTS + n0 + n) * CIN + ch * 8] = v;
    }
  } else if (bid < 1056) {  // ---- prepack xyz2 ----
    int idx = (bid - 1024) * 256 + t;
    int b = idx >> 11, s = idx & (SPTS - 1);
    const float* x2 = xyz2 + (size_t)b * 3 * SPTS;
    float x = x2[s], y = x2[SPTS + s], z = x2[2 * SPTS + s];
    xp[idx] = make_float4(x, y, z, x * x + y * y + z * z);
  } else if (bid < 1184) {  // ---- pack weights ----
    int idx = ((bid - 1056) * 256 + t) * 4;
    const float* src = (idx < H0 * CIN) ? (w0 + idx) : (w1 + (idx - H0 * CIN));
    float4 v = *(const float4*)src;
    ushort4 o;
    o.x = f2bf(v.x); o.y = f2bf(v.y); o.z = f2bf(v.z); o.w = f2bf(v.w);
    *(ushort4*)(Wp + idx) = o;
  } else {  // ---- zero BN stat accumulators (768 floats) ----
    for (int i = t; i < 768; i += 256) stats[i] = 0.f;
  }
}

// branchless top-3 insert: distances via fmin/fmed3, indices via cndmask (EXACT)
#define INS3(d, s, e0, e1, e2, j0, j1, j2)                        \
  {                                                               \
    bool lt0 = (d) < (e0), lt1 = (d) < (e1), lt2 = (d) < (e2);    \
    j2 = lt1 ? (j1) : (lt2 ? (s) : (j2));                         \
    j1 = lt0 ? (j0) : (lt1 ? (s) : (j1));                         \
    j0 = lt0 ? (s) : (j0);                                        \
    e2 = __builtin_amdgcn_fmed3f((d), (e1), (e2));                \
    e1 = __builtin_amdgcn_fmed3f((d), (e0), (e1));                \
    e0 = fminf((d), (e0));                                        \
  }

// ---------------- 3-NN search: 16 waves/block, 128-cand chunks, 2-stage merge ----------------
// Rank on d' = |c|^2 - 2 q.c (per-query |q|^2 offset preserves ordering). EXACT distances.
__global__ __launch_bounds__(1024) void knn_kernel(
    const float* __restrict__ xyz1, const float4* __restrict__ xp,
    int* __restrict__ nidx, float* __restrict__ nw) {
  int b = blockIdx.y;
  int t = threadIdx.x;
  int lane = t & 63;
  int w = __builtin_amdgcn_readfirstlane(t >> 6);  // 0..15, wave-uniform
  int n = blockIdx.x * 64 + lane;
  const float* x1 = xyz1 + (size_t)b * 3 * NPTS;
  float px = x1[n], py = x1[NPTS + n], pz = x1[2 * NPTS + n];

  const int CHUNK = SPTS / 16;  // 128
  int sbase = w * CHUNK;
  const float4* cp = xp + (size_t)b * SPTS + sbase;

  float d0 = 3e38f, d1 = 3e38f, d2 = 3e38f;
  int i0 = 0, i1 = 0, i2 = 0;
#pragma unroll 8
  for (int j = 0; j < CHUNK; j++) {
    float4 c = cp[j];  // wave-uniform address -> scalar load
    float qc = fmaf(py, c.y, px * c.x);
    qc = fmaf(pz, c.z, qc);
    float d = fmaf(-2.f, qc, c.w);
    int s = sbase + j;
    INS3(d, s, d0, d1, d2, i0, i1, i2);
  }

  __shared__ float dsh[16][64][3];
  __shared__ int   ish[16][64][3];
  dsh[w][lane][0] = d0; dsh[w][lane][1] = d1; dsh[w][lane][2] = d2;
  ish[w][lane][0] = i0; ish[w][lane][1] = i1; ish[w][lane][2] = i2;
  __syncthreads();

  // stage B: 4 groups merge 4 lists each (threads 0..255)
  if (t < 256) {
    int g = t >> 6, q = t & 63;
    float e0 = 3e38f, e1 = 3e38f, e2 = 3e38f;
    int j0 = 0, j1 = 0, j2 = 0;
#pragma unroll
    for (int c = 0; c < 4; c++) {
#pragma unroll
      for (int k = 0; k < 3; k++) {
        float d = dsh[4 * g + c][q][k];
        int s = ish[4 * g + c][q][k];
        INS3(d, s, e0, e1, e2, j0, j1, j2);
      }
    }
    dsh[4 * g][q][0] = e0; dsh[4 * g][q][1] = e1; dsh[4 * g][q][2] = e2;
    ish[4 * g][q][0] = j0; ish[4 * g][q][1] = j1; ish[4 * g][q][2] = j2;
  }
  __syncthreads();

  // stage C: final merge of 4 lists (threads 0..63 == wave 0, which owns px/py/pz for n)
  if (t < 64) {
    float e0 = 3e38f, e1 = 3e38f, e2 = 3e38f;
    int j0 = 0, j1 = 0, j2 = 0;
#pragma unroll
    for (int c = 0; c < 4; c++) {
#pragma unroll
      for (int k = 0; k < 3; k++) {
        float d = dsh[4 * c][t][k];
        int s = ish[4 * c][t][k];
        INS3(d, s, e0, e1, e2, j0, j1, j2);
      }
    }
    float qq = px * px + py * py + pz * pz;
    float r0 = 1.f / (e0 + qq + 1e-8f);
    float r1 = 1.f / (e1 + qq + 1e-8f);
    float r2 = 1.f / (e2 + qq + 1e-8f);
    float rs = 1.f / (r0 + r1 + r2);
    int base = (b * NPTS + n) * 3;
    nidx[base + 0] = j0; nidx[base + 1] = j1; nidx[base + 2] = j2;
    nw[base + 0] = r0 * rs; nw[base + 1] = r1 * rs; nw[base + 2] = r2 * rs;
  }
}

// ---------------- interpolation (bf16 gather) -> Xp[b][n][128..383] bf16 ----------------
__global__ __launch_bounds__(256) void interp_kernel(
    const unsigned short* __restrict__ p2tb, const int* __restrict__ nidx,
    const float* __restrict__ nw, unsigned short* __restrict__ Xp) {
  const int PTS = 8;
  int bid = blockIdx.x;
  int b = bid / (NPTS / PTS);
  int p0 = (bid % (NPTS / PTS)) * PTS;
  int c = threadIdx.x;
  const unsigned short* base = p2tb + (size_t)b * SPTS * C2;
#pragma unroll
  for (int k = 0; k < PTS; k++) {
    int p = p0 + k;
    int ib = (b * NPTS + p) * 3;
    int i0 = nidx[ib], i1 = nidx[ib + 1], i2 = nidx[ib + 2];
    float w0v = nw[ib], w1v = nw[ib + 1], w2v = nw[ib + 2];
    float v = w0v * bf2f(base[(size_t)i0 * C2 + c]) +
              w1v * bf2f(base[(size_t)i1 * C2 + c]) +
              w2v * bf2f(base[(size_t)i2 * C2 + c]);
    Xp[((size_t)b * NPTS + p) * CIN + C1 + c] = f2bf(v);
  }
}

// ---------------- MFMA GEMM (m97 structure) + fused BN-stat accumulation ----------------
// Epilogue: per-channel sum / sumsq via 16-lane shfl butterfly + atomicAdd.
template <int MT, int KD, bool OUT_BF16>
__global__ __launch_bounds__(256) void mfma_gemm_kernel(
    const unsigned short* __restrict__ A, const unsigned short* __restrict__ X,
    const float* __restrict__ bias, void* __restrict__ Yv,
    float* __restrict__ sumb, float* __restrict__ sqb) {
  __shared__ unsigned short As[128 * 32];
  __shared__ unsigned short Bs[128 * 32];
  int b = blockIdx.z;
  int n0 = blockIdx.x * 128;
  int o0 = blockIdx.y * 128;
  int t = threadIdx.x;
  int lane = t & 63;
  int w = __builtin_amdgcn_readfirstlane(t >> 6);
  int mhalf = (w & 1) * 64, nhalf = (w >> 1) * 64;
  const unsigned short* Xb = X + (size_t)b * NPTS * KD;

  f32x4 acc[4][4] = {};

  int rA = lane >> 2;
  int cofs = (lane & 3) * 8;

  for (int k0 = 0; k0 < KD; k0 += 32) {
#pragma unroll
    for (int q = 0; q < 2; q++) {
      int r0 = w * 32 + q * 16;
      const unsigned short* ga = A + (size_t)(o0 + r0 + rA) * KD + k0 + cofs;
      __builtin_amdgcn_global_load_lds(
          (const __attribute__((address_space(1))) void*)ga,
          (__attribute__((address_space(3))) void*)(As + r0 * 32), 16, 0, 0);
      const unsigned short* gb = Xb + (size_t)(n0 + r0 + rA) * KD + k0 + cofs;
      __builtin_amdgcn_global_load_lds(
          (const __attribute__((address_space(1))) void*)gb,
          (__attribute__((address_space(3))) void*)(Bs + r0 * 32), 16, 0, 0);
    }
    __syncthreads();

    bf16x8 af[4], bfr[4];
    int mi = lane & 15, kq = (lane >> 4) * 8;
#pragma unroll
    for (int i = 0; i < 4; i++) {
      af[i]  = *(const bf16x8*)(As + (mhalf + i * 16 + mi) * 32 + kq);
      bfr[i] = *(const bf16x8*)(Bs + (nhalf + i * 16 + mi) * 32 + kq);
    }
#pragma unroll
    for (int mt = 0; mt < 4; mt++)
#pragma unroll
      for (int nt = 0; nt < 4; nt++)
        acc[mt][nt] = __builtin_amdgcn_mfma_f32_16x16x32_bf16(
            af[mt], bfr[nt], acc[mt][nt], 0, 0, 0);
    __syncthreads();
  }

  int mi = lane & 15;
  int rq = (lane >> 4) * 4;
#pragma unroll
  for (int mt = 0; mt < 4; mt++) {
#pragma unroll
    for (int r = 0; r < 4; r++) {
      int m = o0 + mhalf + mt * 16 + rq + r;
      float bv = bias[m];
      float ps = 0.f, pq = 0.f;
#pragma unroll
      for (int nt = 0; nt < 4; nt++) {
        int n = n0 + nhalf + nt * 16 + mi;
        float v = acc[mt][nt][r] + bv;
        ps += v; pq += v * v;
        if constexpr (OUT_BF16) {
          unsigned short* Y = (unsigned short*)Yv + (size_t)b * MT * NPTS;
          Y[(size_t)m * NPTS + n] = f2bf(v);
        } else {
          float* Y = (float*)Yv + (size_t)b * MT * NPTS;
          Y[(size_t)m * NPTS + n] = v;
        }
      }
      // all 16 lanes of a rq-group share channel m -> butterfly reduce
#pragma unroll
      for (int off = 1; off < 16; off <<= 1) {
        ps += __shfl_xor(ps, off, 16);
        pq += __shfl_xor(pq, off, 16);
      }
      if (mi == 0) {
        atomicAdd(&sumb[m], ps);
        atomicAdd(&sqb[m], pq);
      }
    }
  }
}

// ---------------- BN0 apply + ReLU + transpose (stats from fused sums) ----------------
__global__ __launch_bounds__(256) void bn0_apply_kernel(
    const unsigned short* __restrict__ Y0, const float* __restrict__ sumb,
    const float* __restrict__ sqb, const float* __restrict__ gamma,
    const float* __restrict__ beta, unsigned short* __restrict__ X1) {
  __shared__ unsigned short tile[64][80];
  __shared__ float aS[64], sS[64];
  int b = blockIdx.z, o0 = blockIdx.y * 64, n0 = blockIdx.x * 64;
  int t = threadIdx.x;
  if (t < 64) {
    const float inv = 1.f / (float)(BATCH * NPTS);
    float mean = sumb[o0 + t] * inv;
    float var = sqb[o0 + t] * inv - mean * mean;
    float ia = gamma[o0 + t] * rsqrtf(var + 1e-5f);
    aS[t] = ia; sS[t] = beta[o0 + t] - mean * ia;
  }
  __syncthreads();
  int nn = t & 63, o4 = t >> 6;
#pragma unroll
  for (int i = 0; i < 16; i++) {
    int o = i * 4 + o4;
    float v = bf2f(Y0[((size_t)b * H0 + o0 + o) * NPTS + n0 + nn]);
    v = fmaxf(v * aS[o] + sS[o], 0.f);
    tile[nn][o] = f2bf(v);
  }
  __syncthreads();
  int n = t >> 2;
#pragma unroll
  for (int j = 0; j < 2; j++) {
    int ch = (t & 3) + j * 4;
    uint4 v = *(const uint4*)&tile[n][ch * 8];
    *(uint4*)&X1[((size_t)b * NPTS + n0 + n) * H0 + o0 + ch * 8] = v;
  }
}

// ---------------- final BN+ReLU in-place on d_out (stats from fused sums) ----------------
__global__ __launch_bounds__(256) void bn_apply_kernel(
    float* __restrict__ Y, const float* __restrict__ sumb,
    const float* __restrict__ sqb, const float* __restrict__ gamma,
    const float* __restrict__ beta) {
  __shared__ float sh2[2];
  int idx0 = blockIdx.x * 1024;          // 1024 contiguous fp32 per block
  int c = (idx0 >> 13) & (H1 - 1);       // single channel per block (1024 | 8192)
  if (threadIdx.x == 0) {
    const float inv = 1.f / (float)(BATCH * NPTS);
    float mean = sumb[c] * inv;
    float var = sqb[c] * inv - mean * mean;
    float ia = gamma[c] * rsqrtf(var + 1e-5f);
    sh2[0] = ia; sh2[1] = beta[c] - mean * ia;
  }
  __syncthreads();
  float ia = sh2[0], sh = sh2[1];
  int i = idx0 + threadIdx.x * 4;
  float4 v = *(float4*)(Y + i);
  v.x = fmaxf(v.x * ia + sh, 0.f);
  v.y = fmaxf(v.y * ia + sh, 0.f);
  v.z = fmaxf(v.z * ia + sh, 0.f);
  v.w = fmaxf(v.w * ia + sh, 0.f);
  *(float4*)(Y + i) = v;
}

extern "C" void kernel_launch(void* const* d_in, const int* in_sizes, int n_in,
                              void* d_out, int out_size, void* d_ws, size_t ws_size,
                              hipStream_t stream) {
  const float* xyz1    = (const float*)d_in[0];
  const float* xyz2    = (const float*)d_in[1];
  const float* points1 = (const float*)d_in[2];
  const float* points2 = (const float*)d_in[3];
  const float* w0      = (const float*)d_in[4];
  const float* b0      = (const float*)d_in[5];
  const float* gamma0  = (const float*)d_in[6];
  const float* beta0   = (const float*)d_in[7];
  const float* w1      = (const float*)d_in[8];
  const float* b1      = (const float*)d_in[9];
  const float* gamma1  = (const float*)d_in[10];
  const float* beta1   = (const float*)d_in[11];
  float* out = (float*)d_out;

  char* ws = (char*)d_ws;
  unsigned short* p2tb = (unsigned short*)ws;  ws += (size_t)BATCH * SPTS * C2 * 2;   // 4.2 MB
  unsigned short* Xp = (unsigned short*)ws;    ws += (size_t)BATCH * NPTS * CIN * 2;  // 25.2 MB
  unsigned short* Y0 = (unsigned short*)ws;    ws += (size_t)BATCH * H0 * NPTS * 2;   // 16.8 MB
  unsigned short* X1 = (unsigned short*)ws;    ws += (size_t)BATCH * NPTS * H0 * 2;   // 16.8 MB
  unsigned short* Wp = (unsigned short*)ws;    ws += (size_t)(H0 * CIN + H1 * H0) * 2;
  int* nidx = (int*)ws;                        ws += (size_t)BATCH * NPTS * 3 * 4;
  float* nw = (float*)ws;                      ws += (size_t)BATCH * NPTS * 3 * 4;
  float4* xyz2p = (float4*)(((uintptr_t)ws + 15) & ~(uintptr_t)15);
  ws = (char*)xyz2p + (size_t)BATCH * SPTS * 16;
  float* stats = (float*)ws;                   ws += 4096;   // 768 floats used
  float* sum0 = stats;          // [256]
  float* sq0  = stats + 256;    // [256]
  float* sum1 = stats + 512;    // [128]
  float* sq1  = stats + 640;    // [128]
  (void)ws_size; (void)in_sizes; (void)n_in; (void)out_size;

  prep_kernel<<<dim3(1185), 256, 0, stream>>>(points2, p2tb, xyz2, xyz2p,
                                              w0, w1, Wp, points1, Xp, stats);
  knn_kernel<<<dim3(NPTS / 64, BATCH), 1024, 0, stream>>>(xyz1, xyz2p, nidx, nw);
  interp_kernel<<<dim3(BATCH * NPTS / 8), 256, 0, stream>>>(p2tb, nidx, nw, Xp);

  mfma_gemm_kernel<H0, CIN, true><<<dim3(NPTS / 128, H0 / 128, BATCH), 256, 0, stream>>>(
      Wp, Xp, b0, Y0, sum0, sq0);
  bn0_apply_kernel<<<dim3(NPTS / 64, H0 / 64, BATCH), 256, 0, stream>>>(
      Y0, sum0, sq0, gamma0, beta0, X1);
  mfma_gemm_kernel<H1, H0, false><<<dim3(NPTS / 128, H1 / 128, BATCH), 256, 0, stream>>>(
      Wp + H0 * CIN, X1, b1, out, sum1, sq1);
  bn_apply_kernel<<<dim3(BATCH * H1 * NPTS / 1024), 256, 0, stream>>>(
      out, sum1, sq1, gamma1, beta1);
}

// Round 3
// 189.092 us; speedup vs baseline: 1.6710x; 1.6710x over previous
//
#include <hip/hip_runtime.h>
#include <hip/hip_bf16.h>

#define BATCH 4
#define NPTS  8192
#define SPTS  2048
#define C1    128
#define C2    256
#define CIN   384   // C1+C2
#define H0    256
#define H1    128
#define NSLICE 32   // BN-stat accumulator slices (atomic contention killer)

typedef __attribute__((ext_vector_type(8))) short bf16x8;
typedef __attribute__((ext_vector_type(4))) float f32x4;

__device__ __forceinline__ unsigned short f2bf(float x) {
  union { float f; unsigned u; } v; v.f = x;
  unsigned r = v.u + 0x7fff + ((v.u >> 16) & 1);   // RNE
  return (unsigned short)(r >> 16);
}
__device__ __forceinline__ float bf2f(unsigned short u) {
  union { unsigned u; float f; } v; v.u = ((unsigned)u) << 16; return v.f;
}

// ---------------- fused prep: all input-only packing in one launch ----------------
// seg A [0,512):    transpose points2 (B,C2,S) fp32 -> p2tb (B,S,C2) bf16
// seg B [512,1024): pack points1 (B,C1,N) fp32 -> Xp[b][n][0..127] bf16
// seg C [1024,1056): prepack xyz2 (B,3,S) -> float4 (x,y,z,|c|^2)
// seg D [1056,1184): weights fp32 -> bf16 (Wp0 256x384, then Wp1 128x256)
// seg E [1184,1208): zero BN stat accumulators (32 slices x 768 floats)
__global__ __launch_bounds__(256) void prep_kernel(
    const float* __restrict__ p2, unsigned short* __restrict__ p2tb,
    const float* __restrict__ xyz2, float4* __restrict__ xp,
    const float* __restrict__ w0, const float* __restrict__ w1,
    unsigned short* __restrict__ Wp,
    const float* __restrict__ p1, unsigned short* __restrict__ Xp,
    float* __restrict__ stats) {
  __shared__ unsigned short shmem[64 * 136];
  int bid = blockIdx.x;
  int t = threadIdx.x;

  if (bid < 512) {  // ---- transpose p2 -> bf16 ----
    int b = bid >> 7, rem = bid & 127;
    int s0 = (rem >> 2) * 64, c0 = (rem & 3) * 64;
    const float* src = p2 + (size_t)b * C2 * SPTS;
    int ss = t & 63, cseg = t >> 6;
#pragma unroll
    for (int i = 0; i < 16; i++) {
      int cc = cseg + i * 4;
      shmem[ss * 72 + cc] = f2bf(src[(size_t)(c0 + cc) * SPTS + s0 + ss]);
    }
    __syncthreads();
    int s = t >> 2, chunk = t & 3;
    uint4 v0 = *(const uint4*)&shmem[s * 72 + chunk * 16];
    uint4 v1 = *(const uint4*)&shmem[s * 72 + chunk * 16 + 8];
    unsigned short* dst = p2tb + (size_t)b * SPTS * C2 + (size_t)(s0 + s) * C2 + c0 + chunk * 16;
    *(uint4*)dst = v0;
    *(uint4*)(dst + 8) = v1;
  } else if (bid < 1024) {  // ---- pack p1 ----
    int b2 = bid - 512;
    int b = b2 >> 7, n0 = (b2 & 127) * 64;
    int nn = t & 63, c4 = t >> 6;
#pragma unroll
    for (int i = 0; i < 32; i++) {
      int c = i * 4 + c4;
      shmem[nn * 136 + c] = f2bf(p1[((size_t)b * C1 + c) * NPTS + n0 + nn]);
    }
    __syncthreads();
    int n = t >> 2;
#pragma unroll
    for (int j = 0; j < 4; j++) {
      int ch = (t & 3) + j * 4;
      uint4 v = *(const uint4*)&shmem[n * 136 + ch * 8];
      *(uint4*)&Xp[((size_t)b * NPTS + n0 + n) * CIN + ch * 8] = v;
    }
  } else if (bid < 1056) {  // ---- prepack xyz2 ----
    int idx = (bid - 1024) * 256 + t;
    int b = idx >> 11, s = idx & (SPTS - 1);
    const float* x2 = xyz2 + (size_t)b * 3 * SPTS;
    float x = x2[s], y = x2[SPTS + s], z = x2[2 * SPTS + s];
    xp[idx] = make_float4(x, y, z, x * x + y * y + z * z);
  } else if (bid < 1184) {  // ---- pack weights ----
    int idx = ((bid - 1056) * 256 + t) * 4;
    const float* src = (idx < H0 * CIN) ? (w0 + idx) : (w1 + (idx - H0 * CIN));
    float4 v = *(const float4*)src;
    ushort4 o;
    o.x = f2bf(v.x); o.y = f2bf(v.y); o.z = f2bf(v.z); o.w = f2bf(v.w);
    *(ushort4*)(Wp + idx) = o;
  } else {  // ---- zero BN stat accumulators (NSLICE*768 floats) ----
    int i4 = ((bid - 1184) * 256 + t) * 4;
    if (i4 < NSLICE * 768) *(float4*)(stats + i4) = make_float4(0.f, 0.f, 0.f, 0.f);
  }
}

// branchless top-3 insert: distances via fmin/fmed3, indices via cndmask (EXACT)
#define INS3(d, s, e0, e1, e2, j0, j1, j2)                        \
  {                                                               \
    bool lt0 = (d) < (e0), lt1 = (d) < (e1), lt2 = (d) < (e2);    \
    j2 = lt1 ? (j1) : (lt2 ? (s) : (j2));                         \
    j1 = lt0 ? (j0) : (lt1 ? (s) : (j1));                         \
    j0 = lt0 ? (s) : (j0);                                        \
    e2 = __builtin_amdgcn_fmed3f((d), (e1), (e2));                \
    e1 = __builtin_amdgcn_fmed3f((d), (e0), (e1));                \
    e0 = fminf((d), (e0));                                        \
  }

// ---------------- 3-NN search: 16 waves/block, 128-cand chunks, 2-stage merge ----------------
__global__ __launch_bounds__(1024) void knn_kernel(
    const float* __restrict__ xyz1, const float4* __restrict__ xp,
    int* __restrict__ nidx, float* __restrict__ nw) {
  int b = blockIdx.y;
  int t = threadIdx.x;
  int lane = t & 63;
  int w = __builtin_amdgcn_readfirstlane(t >> 6);  // 0..15, wave-uniform
  int n = blockIdx.x * 64 + lane;
  const float* x1 = xyz1 + (size_t)b * 3 * NPTS;
  float px = x1[n], py = x1[NPTS + n], pz = x1[2 * NPTS + n];

  const int CHUNK = SPTS / 16;  // 128
  int sbase = w * CHUNK;
  const float4* cp = xp + (size_t)b * SPTS + sbase;

  float d0 = 3e38f, d1 = 3e38f, d2 = 3e38f;
  int i0 = 0, i1 = 0, i2 = 0;
#pragma unroll 8
  for (int j = 0; j < CHUNK; j++) {
    float4 c = cp[j];  // wave-uniform address -> scalar load
    float qc = fmaf(py, c.y, px * c.x);
    qc = fmaf(pz, c.z, qc);
    float d = fmaf(-2.f, qc, c.w);
    int s = sbase + j;
    INS3(d, s, d0, d1, d2, i0, i1, i2);
  }

  __shared__ float dsh[16][64][3];
  __shared__ int   ish[16][64][3];
  dsh[w][lane][0] = d0; dsh[w][lane][1] = d1; dsh[w][lane][2] = d2;
  ish[w][lane][0] = i0; ish[w][lane][1] = i1; ish[w][lane][2] = i2;
  __syncthreads();

  if (t < 256) {
    int g = t >> 6, q = t & 63;
    float e0 = 3e38f, e1 = 3e38f, e2 = 3e38f;
    int j0 = 0, j1 = 0, j2 = 0;
#pragma unroll
    for (int c = 0; c < 4; c++) {
#pragma unroll
      for (int k = 0; k < 3; k++) {
        float d = dsh[4 * g + c][q][k];
        int s = ish[4 * g + c][q][k];
        INS3(d, s, e0, e1, e2, j0, j1, j2);
      }
    }
    dsh[4 * g][q][0] = e0; dsh[4 * g][q][1] = e1; dsh[4 * g][q][2] = e2;
    ish[4 * g][q][0] = j0; ish[4 * g][q][1] = j1; ish[4 * g][q][2] = j2;
  }
  __syncthreads();

  if (t < 64) {
    float e0 = 3e38f, e1 = 3e38f, e2 = 3e38f;
    int j0 = 0, j1 = 0, j2 = 0;
#pragma unroll
    for (int c = 0; c < 4; c++) {
#pragma unroll
      for (int k = 0; k < 3; k++) {
        float d = dsh[4 * c][t][k];
        int s = ish[4 * c][t][k];
        INS3(d, s, e0, e1, e2, j0, j1, j2);
      }
    }
    float qq = px * px + py * py + pz * pz;
    float r0 = 1.f / (e0 + qq + 1e-8f);
    float r1 = 1.f / (e1 + qq + 1e-8f);
    float r2 = 1.f / (e2 + qq + 1e-8f);
    float rs = 1.f / (r0 + r1 + r2);
    int base = (b * NPTS + n) * 3;
    nidx[base + 0] = j0; nidx[base + 1] = j1; nidx[base + 2] = j2;
    nw[base + 0] = r0 * rs; nw[base + 1] = r1 * rs; nw[base + 2] = r2 * rs;
  }
}

// ---------------- interpolation (bf16 gather) -> Xp[b][n][128..383] bf16 ----------------
__global__ __launch_bounds__(256) void interp_kernel(
    const unsigned short* __restrict__ p2tb, const int* __restrict__ nidx,
    const float* __restrict__ nw, unsigned short* __restrict__ Xp) {
  const int PTS = 8;
  int bid = blockIdx.x;
  int b = bid / (NPTS / PTS);
  int p0 = (bid % (NPTS / PTS)) * PTS;
  int c = threadIdx.x;
  const unsigned short* base = p2tb + (size_t)b * SPTS * C2;
#pragma unroll
  for (int k = 0; k < PTS; k++) {
    int p = p0 + k;
    int ib = (b * NPTS + p) * 3;
    int i0 = nidx[ib], i1 = nidx[ib + 1], i2 = nidx[ib + 2];
    float w0v = nw[ib], w1v = nw[ib + 1], w2v = nw[ib + 2];
    float v = w0v * bf2f(base[(size_t)i0 * C2 + c]) +
              w1v * bf2f(base[(size_t)i1 * C2 + c]) +
              w2v * bf2f(base[(size_t)i2 * C2 + c]);
    Xp[((size_t)b * NPTS + p) * CIN + C1 + c] = f2bf(v);
  }
}

// ---------------- MFMA GEMM: 2-phase double-buffered prefetch + sliced BN stats ----------------
template <int MT, int KD, bool OUT_BF16>
__global__ __launch_bounds__(256) void mfma_gemm_kernel(
    const unsigned short* __restrict__ A, const unsigned short* __restrict__ X,
    const float* __restrict__ bias, void* __restrict__ Yv,
    float* __restrict__ stats, int sum_off, int sq_off) {
  __shared__ unsigned short As[2][128 * 32];
  __shared__ unsigned short Bs[2][128 * 32];
  int b = blockIdx.z;
  int n0 = blockIdx.x * 128;
  int o0 = blockIdx.y * 128;
  int t = threadIdx.x;
  int lane = t & 63;
  int w = __builtin_amdgcn_readfirstlane(t >> 6);
  int mhalf = (w & 1) * 64, nhalf = (w >> 1) * 64;
  const unsigned short* Xb = X + (size_t)b * NPTS * KD;

  int rA = lane >> 2;
  int cofs = (lane & 3) * 8;

  // stage one 128x32 A-tile + B-tile pair into buffer `buf`
  auto stage = [&](int buf, int k0) {
#pragma unroll
    for (int q = 0; q < 2; q++) {
      int r0 = w * 32 + q * 16;
      const unsigned short* ga = A + (size_t)(o0 + r0 + rA) * KD + k0 + cofs;
      __builtin_amdgcn_global_load_lds(
          (const __attribute__((address_space(1))) void*)ga,
          (__attribute__((address_space(3))) void*)(&As[buf][r0 * 32]), 16, 0, 0);
      const unsigned short* gb = Xb + (size_t)(n0 + r0 + rA) * KD + k0 + cofs;
      __builtin_amdgcn_global_load_lds(
          (const __attribute__((address_space(1))) void*)gb,
          (__attribute__((address_space(3))) void*)(&Bs[buf][r0 * 32]), 16, 0, 0);
    }
  };

  f32x4 acc[4][4] = {};
  int mi = lane & 15, kq = (lane >> 4) * 8;

  stage(0, 0);
  __syncthreads();          // drains vmcnt(0): tile 0 landed

  int cur = 0;
  for (int k0 = 0; k0 < KD; k0 += 32) {
    if (k0 + 32 < KD) stage(cur ^ 1, k0 + 32);  // issue next-tile loads BEFORE compute

    bf16x8 af[4], bfr[4];
#pragma unroll
    for (int i = 0; i < 4; i++) {
      af[i]  = *(const bf16x8*)(&As[cur][(mhalf + i * 16 + mi) * 32 + kq]);
      bfr[i] = *(const bf16x8*)(&Bs[cur][(nhalf + i * 16 + mi) * 32 + kq]);
    }
#pragma unroll
    for (int mt = 0; mt < 4; mt++)
#pragma unroll
      for (int nt = 0; nt < 4; nt++)
        acc[mt][nt] = __builtin_amdgcn_mfma_f32_16x16x32_bf16(
            af[mt], bfr[nt], acc[mt][nt], 0, 0, 0);
    __syncthreads();        // drains vmcnt(0) (next tile landed) + all ds reads done
    cur ^= 1;
  }

  int slice = ((blockIdx.x << 2) + blockIdx.z) & (NSLICE - 1);
  float* sb = stats + slice * 768 + sum_off;
  float* qb = stats + slice * 768 + sq_off;

  int rq = (lane >> 4) * 4;
#pragma unroll
  for (int mt = 0; mt < 4; mt++) {
#pragma unroll
    for (int r = 0; r < 4; r++) {
      int m = o0 + mhalf + mt * 16 + rq + r;
      float bv = bias[m];
      float ps = 0.f, pq = 0.f;
#pragma unroll
      for (int nt = 0; nt < 4; nt++) {
        int n = n0 + nhalf + nt * 16 + mi;
        float v = acc[mt][nt][r] + bv;
        ps += v; pq += v * v;
        if constexpr (OUT_BF16) {
          unsigned short* Y = (unsigned short*)Yv + (size_t)b * MT * NPTS;
          Y[(size_t)m * NPTS + n] = f2bf(v);
        } else {
          float* Y = (float*)Yv + (size_t)b * MT * NPTS;
          Y[(size_t)m * NPTS + n] = v;
        }
      }
      // 16 lanes of a rq-group share channel m -> butterfly reduce, 1 atomic pair
#pragma unroll
      for (int off = 1; off < 16; off <<= 1) {
        ps += __shfl_xor(ps, off, 16);
        pq += __shfl_xor(pq, off, 16);
      }
      if (mi == 0) {
        atomicAdd(&sb[m], ps);
        atomicAdd(&qb[m], pq);
      }
    }
  }
}

// ---------------- BN0 apply + ReLU + transpose (stats from 32 slices) ----------------
__global__ __launch_bounds__(256) void bn0_apply_kernel(
    const unsigned short* __restrict__ Y0, const float* __restrict__ stats,
    const float* __restrict__ gamma, const float* __restrict__ beta,
    unsigned short* __restrict__ X1) {
  __shared__ unsigned short tile[64][80];
  __shared__ float aS[64], sS[64];
  int b = blockIdx.z, o0 = blockIdx.y * 64, n0 = blockIdx.x * 64;
  int t = threadIdx.x;
  if (t < 64) {
    float ms = 0.f, vs = 0.f;
#pragma unroll
    for (int sl = 0; sl < NSLICE; sl++) {
      ms += stats[sl * 768 + o0 + t];
      vs += stats[sl * 768 + 256 + o0 + t];
    }
    const float inv = 1.f / (float)(BATCH * NPTS);
    float mean = ms * inv;
    float var = vs * inv - mean * mean;
    float ia = gamma[o0 + t] * rsqrtf(var + 1e-5f);
    aS[t] = ia; sS[t] = beta[o0 + t] - mean * ia;
  }
  __syncthreads();
  int nn = t & 63, o4 = t >> 6;
#pragma unroll
  for (int i = 0; i < 16; i++) {
    int o = i * 4 + o4;
    float v = bf2f(Y0[((size_t)b * H0 + o0 + o) * NPTS + n0 + nn]);
    v = fmaxf(v * aS[o] + sS[o], 0.f);
    tile[nn][o] = f2bf(v);
  }
  __syncthreads();
  int n = t >> 2;
#pragma unroll
  for (int j = 0; j < 2; j++) {
    int ch = (t & 3) + j * 4;
    uint4 v = *(const uint4*)&tile[n][ch * 8];
    *(uint4*)&X1[((size_t)b * NPTS + n0 + n) * H0 + o0 + ch * 8] = v;
  }
}

// ---------------- final BN+ReLU in-place on d_out (stats from 32 slices) ----------------
__global__ __launch_bounds__(256) void bn_apply_kernel(
    float* __restrict__ Y, const float* __restrict__ stats,
    const float* __restrict__ gamma, const float* __restrict__ beta) {
  __shared__ float sh2[2];
  int idx0 = blockIdx.x * 1024;          // 1024 contiguous fp32 per block
  int c = (idx0 >> 13) & (H1 - 1);       // single channel per block (1024 | 8192)
  int t = threadIdx.x;
  if (t < 32) {
    float ms = stats[t * 768 + 512 + c];
    float vs = stats[t * 768 + 640 + c];
#pragma unroll
    for (int off = 16; off > 0; off >>= 1) {
      ms += __shfl_down(ms, off, 32);
      vs += __shfl_down(vs, off, 32);
    }
    if (t == 0) {
      const float inv = 1.f / (float)(BATCH * NPTS);
      float mean = ms * inv;
      float var = vs * inv - mean * mean;
      float ia = gamma[c] * rsqrtf(var + 1e-5f);
      sh2[0] = ia; sh2[1] = beta[c] - mean * ia;
    }
  }
  __syncthreads();
  float ia = sh2[0], sh = sh2[1];
  int i = idx0 + t * 4;
  float4 v = *(float4*)(Y + i);
  v.x = fmaxf(v.x * ia + sh, 0.f);
  v.y = fmaxf(v.y * ia + sh, 0.f);
  v.z = fmaxf(v.z * ia + sh, 0.f);
  v.w = fmaxf(v.w * ia + sh, 0.f);
  *(float4*)(Y + i) = v;
}

extern "C" void kernel_launch(void* const* d_in, const int* in_sizes, int n_in,
                              void* d_out, int out_size, void* d_ws, size_t ws_size,
                              hipStream_t stream) {
  const float* xyz1    = (const float*)d_in[0];
  const float* xyz2    = (const float*)d_in[1];
  const float* points1 = (const float*)d_in[2];
  const float* points2 = (const float*)d_in[3];
  const float* w0      = (const float*)d_in[4];
  const float* b0      = (const float*)d_in[5];
  const float* gamma0  = (const float*)d_in[6];
  const float* beta0   = (const float*)d_in[7];
  const float* w1      = (const float*)d_in[8];
  const float* b1      = (const float*)d_in[9];
  const float* gamma1  = (const float*)d_in[10];
  const float* beta1   = (const float*)d_in[11];
  float* out = (float*)d_out;

  char* ws = (char*)d_ws;
  unsigned short* p2tb = (unsigned short*)ws;  ws += (size_t)BATCH * SPTS * C2 * 2;   // 4.2 MB
  unsigned short* Xp = (unsigned short*)ws;    ws += (size_t)BATCH * NPTS * CIN * 2;  // 25.2 MB
  unsigned short* Y0 = (unsigned short*)ws;    ws += (size_t)BATCH * H0 * NPTS * 2;   // 16.8 MB
  unsigned short* X1 = (unsigned short*)ws;    ws += (size_t)BATCH * NPTS * H0 * 2;   // 16.8 MB
  unsigned short* Wp = (unsigned short*)ws;    ws += (size_t)(H0 * CIN + H1 * H0) * 2;
  int* nidx = (int*)ws;                        ws += (size_t)BATCH * NPTS * 3 * 4;
  float* nw = (float*)ws;                      ws += (size_t)BATCH * NPTS * 3 * 4;
  float4* xyz2p = (float4*)(((uintptr_t)ws + 15) & ~(uintptr_t)15);
  ws = (char*)xyz2p + (size_t)BATCH * SPTS * 16;
  float* stats = (float*)ws;                   ws += (size_t)NSLICE * 768 * 4;  // 96 KB
  // per-slice layout: [0,256)=sum0, [256,512)=sq0, [512,640)=sum1, [640,768)=sq1
  (void)ws_size; (void)in_sizes; (void)n_in; (void)out_size;

  prep_kernel<<<dim3(1208), 256, 0, stream>>>(points2, p2tb, xyz2, xyz2p,
                                              w0, w1, Wp, points1, Xp, stats);
  knn_kernel<<<dim3(NPTS / 64, BATCH), 1024, 0, stream>>>(xyz1, xyz2p, nidx, nw);
  interp_kernel<<<dim3(BATCH * NPTS / 8), 256, 0, stream>>>(p2tb, nidx, nw, Xp);

  mfma_gemm_kernel<H0, CIN, true><<<dim3(NPTS / 128, H0 / 128, BATCH), 256, 0, stream>>>(
      Wp, Xp, b0, Y0, stats, 0, 256);
  bn0_apply_kernel<<<dim3(NPTS / 64, H0 / 64, BATCH), 256, 0, stream>>>(
      Y0, stats, gamma0, beta0, X1);
  mfma_gemm_kernel<H1, H0, false><<<dim3(NPTS / 128, H1 / 128, BATCH), 256, 0, stream>>>(
      Wp + H0 * CIN, X1, b1, out, stats, 512, 640);
  bn_apply_kernel<<<dim3(BATCH * H1 * NPTS / 1024), 256, 0, stream>>>(
      out, stats, gamma1, beta1);
}